// Round 1
// baseline (2466.030 us; speedup 1.0000x reference)
//
#include <hip/hip_runtime.h>

// STGAN fused forward for MI355X. Shapes fixed per reference.
constexpr int cB = 4, cT = 24, cN = 10000, cF = 64, cE = 160000, cHID = 128, cK = 3;

// ---------- edge dtype detection (int32 vs int64 pushed buffer) ----------
__global__ void k_zero(int* c) { *c = 0; }

__global__ void k_detect(const int* __restrict__ edges, int* __restrict__ cnt) {
    int i = blockIdx.x * 256 + threadIdx.x;
    int z = (i < cE && edges[2 * i + 1] == 0) ? 1 : 0;
    __shared__ int sc;
    if (threadIdx.x == 0) sc = 0;
    __syncthreads();
    if (z) atomicAdd(&sc, 1);
    __syncthreads();
    if (threadIdx.x == 0 && sc) atomicAdd(cnt, sc);
}

__global__ void k_flag(const int* __restrict__ cnt, int* __restrict__ flag) {
    // if (virtually) all odd int32 words are zero, buffer is little-endian int64
    *flag = (*cnt > cE - 100) ? 2 : 1;
}

// ---------- hor_ctx = mean(horizon,1) @ W_hor + b_enc ----------
__global__ void k_hc(const float* __restrict__ horizon, const float* __restrict__ W_hor,
                     const float* __restrict__ b_enc, float* __restrict__ hc) {
    int g = threadIdx.x & 63;
    int sub = threadIdx.x >> 6;
    int pair = blockIdx.x * 4 + sub;          // b*N + n
    __shared__ float sm[4][64];
    bool ok = pair < cB * cN;
    float m = 0.f;
    if (ok) {
        int b = pair / cN, n = pair % cN;
        const float* hp = horizon + ((b * 6) * cN + n) * 64 + g;
        #pragma unroll
        for (int hh = 0; hh < 6; hh++) m += hp[hh * cN * 64];
        m *= (1.0f / 6.0f);
    }
    sm[sub][g] = m;
    __syncthreads();
    if (!ok) return;
    float a = b_enc[g];
    for (int f = 0; f < 64; f++) a = fmaf(sm[sub][f], W_hor[f * 64 + g], a);
    hc[pair * 64 + g] = a;
}

// ---------- fused encode (tanh(hist@W_enc + hc)) + partial MLP accumulate ----------
// block: 512 threads = 8 waves; 64-node tile; wave w owns g-range w*8..w*8+7 (encode)
// and j-range w*16..w*16+15 (MLP accumulator). node == lane.
__launch_bounds__(512, 4)
__global__ void k_encode_mlp(const float* __restrict__ history, const float* __restrict__ W_enc,
                             const float* __restrict__ hc, const float* __restrict__ W1,
                             float* __restrict__ accbuf, float* __restrict__ h0) {
    __shared__ float sWenc[64 * 64];   // 16 KB, resident
    __shared__ float sBuf[64 * 64];    // 16 KB, hist tile (transposed+xor) then xe tile
    __shared__ float sW1[32 * cHID];   // 16 KB, half of W1_t streamed
    const int tid = threadIdx.x;
    const int lane = tid & 63;
    const int w = tid >> 6;
    const int n0 = blockIdx.x * 64;
    const int b = blockIdx.y;
    const int nn = min(64, cN - n0);
    const bool has = lane < nn;
    const int nodeBase = b * cN + n0;

    {   // W_enc once
        const float4* src = (const float4*)W_enc;
        float4* dst = (float4*)sWenc;
        dst[tid] = src[tid];
        dst[tid + 512] = src[tid + 512];
    }
    float hcr[8];
    if (has) {
        const float* hp = hc + (nodeBase + lane) * 64 + w * 8;
        float4 a = *(const float4*)hp;
        float4 c = *(const float4*)(hp + 4);
        hcr[0] = a.x; hcr[1] = a.y; hcr[2] = a.z; hcr[3] = a.w;
        hcr[4] = c.x; hcr[5] = c.y; hcr[6] = c.z; hcr[7] = c.w;
    } else {
        #pragma unroll
        for (int j = 0; j < 8; j++) hcr[j] = 0.f;
    }
    float acc[16];
    #pragma unroll
    for (int j = 0; j < 16; j++) acc[j] = 0.f;

    for (int t = 0; t < cT; t++) {
        __syncthreads();   // sBuf reuse vs previous iteration readers
        {   // stage hist tile transposed with xor swizzle: sBuf[f*64 + (node^f&31)]
            const float* hsrc = history + ((b * cT + t) * cN + n0) * 64;
            #pragma unroll
            for (int r = 0; r < 2; r++) {
                int i = tid * 2 + r;            // float4 index 0..1023
                int node = i >> 4, fq = i & 15;
                float4 v = make_float4(0.f, 0.f, 0.f, 0.f);
                if (node < nn) v = *(const float4*)(hsrc + node * 64 + fq * 4);
                int f0 = fq * 4;
                sBuf[(f0 + 0) * 64 + (node ^ ((f0 + 0) & 31))] = v.x;
                sBuf[(f0 + 1) * 64 + (node ^ ((f0 + 1) & 31))] = v.y;
                sBuf[(f0 + 2) * 64 + (node ^ ((f0 + 2) & 31))] = v.z;
                sBuf[(f0 + 3) * 64 + (node ^ ((f0 + 3) & 31))] = v.w;
            }
        }
        __syncthreads();
        // encode: xe[g=w*8+j] for node=lane
        float xe[8];
        #pragma unroll
        for (int j = 0; j < 8; j++) xe[j] = hcr[j];
        for (int f = 0; f < 64; f++) {
            float hv = sBuf[f * 64 + (lane ^ (f & 31))];
            const float* wp = &sWenc[f * 64 + w * 8];
            #pragma unroll
            for (int j = 0; j < 8; j++) xe[j] = fmaf(hv, wp[j], xe[j]);
        }
        #pragma unroll
        for (int j = 0; j < 8; j++) xe[j] = tanhf(xe[j]);

        if (t == cT - 1) {
            if (has) {   // store pre-GCN h slice; its W1 contribution happens in k_head
                float* hp = h0 + (nodeBase + lane) * 64 + w * 8;
                *(float4*)hp = make_float4(xe[0], xe[1], xe[2], xe[3]);
                *(float4*)(hp + 4) = make_float4(xe[4], xe[5], xe[6], xe[7]);
            }
        } else {
            __syncthreads();   // all encode reads of sBuf done
            #pragma unroll
            for (int j = 0; j < 8; j++) sBuf[(w * 8 + j) * 64 + lane] = xe[j];
            #pragma unroll
            for (int half = 0; half < 2; half++) {
                __syncthreads();   // xe writes done / previous half's sW1 reads done
                {
                    const float4* src = (const float4*)(W1 + (t * 64 + half * 32) * cHID);
                    float4* dst = (float4*)sW1;
                    dst[tid] = src[tid];
                    dst[tid + 512] = src[tid + 512];
                }
                __syncthreads();
                #pragma unroll 4
                for (int g = 0; g < 32; g++) {
                    float xv = sBuf[(half * 32 + g) * 64 + lane];
                    const float* wp = &sW1[g * cHID + w * 16];
                    #pragma unroll
                    for (int j = 0; j < 16; j++) acc[j] = fmaf(xv, wp[j], acc[j]);
                }
            }
        }
    }
    if (has) {
        float* ap = accbuf + (nodeBase + lane) * cHID + w * 16;
        #pragma unroll
        for (int j = 0; j < 16; j += 4)
            *(float4*)(ap + j) = make_float4(acc[j], acc[j + 1], acc[j + 2], acc[j + 3]);
    }
}

// ---------- graph norm ----------
__global__ void k_deg_init(float* __restrict__ deg) {
    int n = blockIdx.x * 256 + threadIdx.x;
    if (n < cN) deg[n] = 1.0f;   // self-loop
}
__global__ void k_deg_count(const int* __restrict__ edges, const int* __restrict__ flag,
                            float* __restrict__ deg) {
    int e = blockIdx.x * 256 + threadIdx.x;
    if (e < cE) {
        int m = *flag;
        atomicAdd(&deg[edges[m * (cE + e)]], 1.0f);
    }
}
__global__ void k_dinv(const float* __restrict__ deg, float* __restrict__ dinv) {
    int n = blockIdx.x * 256 + threadIdx.x;
    if (n < cN) dinv[n] = rsqrtf(deg[n]);
}
__global__ void k_norm(const int* __restrict__ edges, const int* __restrict__ flag,
                       const float* __restrict__ dinv, float* __restrict__ norm) {
    int e = blockIdx.x * 256 + threadIdx.x;
    if (e < cE) {
        int m = *flag;
        norm[e] = dinv[edges[m * e]] * dinv[edges[m * (cE + e)]];
    }
}

// ---------- GCN step: xfc = h@W_fc ; hnext = b_gcn + dinv^2*xfc (self-loop) ----------
__global__ void k_fc(const float* __restrict__ h, const float* __restrict__ W_fc,
                     const float* __restrict__ b_gcn, const float* __restrict__ dinv,
                     float* __restrict__ xfc, float* __restrict__ hnext) {
    int g = threadIdx.x & 63, sub = threadIdx.x >> 6;
    int pair = blockIdx.x * 4 + sub;
    __shared__ float sh[4][64];
    bool ok = pair < cB * cN;
    float hv = 0.f;
    if (ok) hv = h[pair * 64 + g];
    sh[sub][g] = hv;
    __syncthreads();
    if (!ok) return;
    float a = 0.f;
    for (int f = 0; f < 64; f++) a = fmaf(sh[sub][f], W_fc[f * 64 + g], a);
    int n = pair % cN;
    float di = dinv[n];
    xfc[pair * 64 + g] = a;
    hnext[pair * 64 + g] = b_gcn[g] + di * di * a;
}

__global__ void k_scatter(const int* __restrict__ edges, const int* __restrict__ flag,
                          const float* __restrict__ norm, const float* __restrict__ xfc,
                          float* __restrict__ hnext) {
    int idx = blockIdx.x * 256 + threadIdx.x;   // e*16 + q
    if (idx >= cE * 16) return;
    int b = blockIdx.y;
    int e = idx >> 4, q = idx & 15;
    int m = *flag;
    int r = edges[m * e], c = edges[m * (cE + e)];
    float nm = norm[e];
    const float4 v = *(const float4*)(xfc + (b * cN + r) * 64 + q * 4);
    float* dst = hnext + (b * cN + c) * 64 + q * 4;
    atomicAdd(dst + 0, nm * v.x);
    atomicAdd(dst + 1, nm * v.y);
    atomicAdd(dst + 2, nm * v.z);
    atomicAdd(dst + 3, nm * v.w);
}

// ---------- head: out = relu(acc + h_fin@W1_{T-1} + b1) @ W2 + b2 ----------
__global__ void k_head(const float* __restrict__ accbuf, const float* __restrict__ hfin,
                       const float* __restrict__ W1, const float* __restrict__ b1,
                       const float* __restrict__ W2, const float* __restrict__ b2,
                       float* __restrict__ out) {
    int pair = blockIdx.x;
    int j = threadIdx.x;   // 0..127
    __shared__ float sh[64];
    __shared__ float red[128];
    if (j < 64) sh[j] = hfin[pair * 64 + j];
    __syncthreads();
    float a = accbuf[pair * cHID + j] + b1[j];
    const float* wp = W1 + (cT - 1) * 64 * cHID + j;
    for (int f = 0; f < 64; f++) a = fmaf(sh[f], wp[f * cHID], a);
    a = fmaxf(a, 0.f) * W2[j];
    red[j] = a;
    __syncthreads();
    for (int s = 64; s > 0; s >>= 1) {
        if (j < s) red[j] += red[j + s];
        __syncthreads();
    }
    if (j == 0) out[pair] = red[0] + b2[0];
}

extern "C" void kernel_launch(void* const* d_in, const int* in_sizes, int n_in,
                              void* d_out, int out_size, void* d_ws, size_t ws_size,
                              hipStream_t stream) {
    const float* history = (const float*)d_in[0];
    const float* horizon = (const float*)d_in[1];
    const int*   edges   = (const int*)d_in[2];
    const float* W_enc   = (const float*)d_in[3];
    const float* W_hor   = (const float*)d_in[4];
    const float* b_enc   = (const float*)d_in[5];
    const float* W_fc    = (const float*)d_in[6];
    const float* b_gcn   = (const float*)d_in[7];
    const float* W1      = (const float*)d_in[8];
    const float* b1      = (const float*)d_in[9];
    const float* W2      = (const float*)d_in[10];
    const float* b2      = (const float*)d_in[11];
    float* out = (float*)d_out;

    float* ws = (float*)d_ws;
    float* hc     = ws;                               // B*N*64
    float* accbuf = hc + (size_t)cB * cN * 64;        // B*N*128
    float* h0     = accbuf + (size_t)cB * cN * cHID;  // B*N*64
    float* h1     = h0 + (size_t)cB * cN * 64;        // B*N*64
    float* xfc    = h1 + (size_t)cB * cN * 64;        // B*N*64
    float* deg    = xfc + (size_t)cB * cN * 64;       // N
    float* dinv   = deg + cN;                         // N
    float* norm   = dinv + cN;                        // E
    int*   cnt    = (int*)(norm + cE);
    int*   flag   = cnt + 1;

    k_zero<<<1, 1, 0, stream>>>(cnt);
    k_detect<<<(cE + 255) / 256, 256, 0, stream>>>(edges, cnt);
    k_flag<<<1, 1, 0, stream>>>(cnt, flag);

    k_hc<<<(cB * cN + 3) / 4, 256, 0, stream>>>(horizon, W_hor, b_enc, hc);
    k_encode_mlp<<<dim3((cN + 63) / 64, cB), 512, 0, stream>>>(history, W_enc, hc, W1, accbuf, h0);

    k_deg_init<<<(cN + 255) / 256, 256, 0, stream>>>(deg);
    k_deg_count<<<(cE + 255) / 256, 256, 0, stream>>>(edges, flag, deg);
    k_dinv<<<(cN + 255) / 256, 256, 0, stream>>>(deg, dinv);
    k_norm<<<(cE + 255) / 256, 256, 0, stream>>>(edges, flag, dinv, norm);

    float* hin = h0; float* hout = h1;
    for (int s = 0; s < cK; s++) {
        k_fc<<<(cB * cN + 3) / 4, 256, 0, stream>>>(hin, W_fc, b_gcn, dinv, xfc, hout);
        k_scatter<<<dim3((cE * 16 + 255) / 256, cB), 256, 0, stream>>>(edges, flag, norm, xfc, hout);
        float* tmp = hin; hin = hout; hout = tmp;
    }

    k_head<<<cB * cN, 128, 0, stream>>>(accbuf, hin, W1, b1, W2, b2, out);
}

// Round 2
// 993.669 us; speedup vs baseline: 2.4817x; 2.4817x over previous
//
#include <hip/hip_runtime.h>

// STGAN fused forward for MI355X. Shapes fixed per reference.
constexpr int cB = 4, cT = 24, cN = 10000, cF = 64, cE = 160000, cHID = 128, cK = 3;

// ---------- edge dtype detection (int32 vs int64 pushed buffer) ----------
__global__ void k_zero(int* c) { *c = 0; }

__global__ void k_detect(const int* __restrict__ edges, int* __restrict__ cnt) {
    int i = blockIdx.x * 256 + threadIdx.x;
    int z = (i < cE && edges[2 * i + 1] == 0) ? 1 : 0;
    __shared__ int sc;
    if (threadIdx.x == 0) sc = 0;
    __syncthreads();
    if (z) atomicAdd(&sc, 1);
    __syncthreads();
    if (threadIdx.x == 0 && sc) atomicAdd(cnt, sc);
}

__global__ void k_flag(const int* __restrict__ cnt, int* __restrict__ flag) {
    // if (virtually) all odd int32 words are zero, buffer is little-endian int64
    *flag = (*cnt > cE - 100) ? 2 : 1;
}

// ---------- hor_ctx = mean(horizon,1) @ W_hor + b_enc ----------
__global__ void k_hc(const float* __restrict__ horizon, const float* __restrict__ W_hor,
                     const float* __restrict__ b_enc, float* __restrict__ hc) {
    int g = threadIdx.x & 63;
    int sub = threadIdx.x >> 6;
    int pair = blockIdx.x * 4 + sub;          // b*N + n
    __shared__ float sm[4][64];
    bool ok = pair < cB * cN;
    float m = 0.f;
    if (ok) {
        int b = pair / cN, n = pair % cN;
        const float* hp = horizon + ((b * 6) * cN + n) * 64 + g;
        #pragma unroll
        for (int hh = 0; hh < 6; hh++) m += hp[hh * cN * 64];
        m *= (1.0f / 6.0f);
    }
    sm[sub][g] = m;
    __syncthreads();
    if (!ok) return;
    float a = b_enc[g];
    for (int f = 0; f < 64; f++) a = fmaf(sm[sub][f], W_hor[f * 64 + g], a);
    hc[pair * 64 + g] = a;
}

// ---------- fused encode (tanh(hist@W_enc + hc)) + partial MLP accumulate ----------
__launch_bounds__(512, 4)
__global__ void k_encode_mlp(const float* __restrict__ history, const float* __restrict__ W_enc,
                             const float* __restrict__ hc, const float* __restrict__ W1,
                             float* __restrict__ accbuf, float* __restrict__ h0) {
    __shared__ float sWenc[64 * 64];   // 16 KB, resident
    __shared__ float sBuf[64 * 64];    // 16 KB, hist tile (transposed+xor) then xe tile
    __shared__ float sW1[32 * cHID];   // 16 KB, half of W1_t streamed
    const int tid = threadIdx.x;
    const int lane = tid & 63;
    const int w = tid >> 6;
    const int n0 = blockIdx.x * 64;
    const int b = blockIdx.y;
    const int nn = min(64, cN - n0);
    const bool has = lane < nn;
    const int nodeBase = b * cN + n0;

    {   // W_enc once
        const float4* src = (const float4*)W_enc;
        float4* dst = (float4*)sWenc;
        dst[tid] = src[tid];
        dst[tid + 512] = src[tid + 512];
    }
    float hcr[8];
    if (has) {
        const float* hp = hc + (nodeBase + lane) * 64 + w * 8;
        float4 a = *(const float4*)hp;
        float4 c = *(const float4*)(hp + 4);
        hcr[0] = a.x; hcr[1] = a.y; hcr[2] = a.z; hcr[3] = a.w;
        hcr[4] = c.x; hcr[5] = c.y; hcr[6] = c.z; hcr[7] = c.w;
    } else {
        #pragma unroll
        for (int j = 0; j < 8; j++) hcr[j] = 0.f;
    }
    float acc[16];
    #pragma unroll
    for (int j = 0; j < 16; j++) acc[j] = 0.f;

    for (int t = 0; t < cT; t++) {
        __syncthreads();   // sBuf reuse vs previous iteration readers
        {   // stage hist tile transposed with xor swizzle: sBuf[f*64 + (node^f&31)]
            const float* hsrc = history + ((b * cT + t) * cN + n0) * 64;
            #pragma unroll
            for (int r = 0; r < 2; r++) {
                int i = tid * 2 + r;            // float4 index 0..1023
                int node = i >> 4, fq = i & 15;
                float4 v = make_float4(0.f, 0.f, 0.f, 0.f);
                if (node < nn) v = *(const float4*)(hsrc + node * 64 + fq * 4);
                int f0 = fq * 4;
                sBuf[(f0 + 0) * 64 + (node ^ ((f0 + 0) & 31))] = v.x;
                sBuf[(f0 + 1) * 64 + (node ^ ((f0 + 1) & 31))] = v.y;
                sBuf[(f0 + 2) * 64 + (node ^ ((f0 + 2) & 31))] = v.z;
                sBuf[(f0 + 3) * 64 + (node ^ ((f0 + 3) & 31))] = v.w;
            }
        }
        __syncthreads();
        // encode: xe[g=w*8+j] for node=lane
        float xe[8];
        #pragma unroll
        for (int j = 0; j < 8; j++) xe[j] = hcr[j];
        for (int f = 0; f < 64; f++) {
            float hv = sBuf[f * 64 + (lane ^ (f & 31))];
            const float* wp = &sWenc[f * 64 + w * 8];
            #pragma unroll
            for (int j = 0; j < 8; j++) xe[j] = fmaf(hv, wp[j], xe[j]);
        }
        #pragma unroll
        for (int j = 0; j < 8; j++) xe[j] = tanhf(xe[j]);

        if (t == cT - 1) {
            if (has) {   // store pre-GCN h slice; its W1 contribution happens in k_head
                float* hp = h0 + (nodeBase + lane) * 64 + w * 8;
                *(float4*)hp = make_float4(xe[0], xe[1], xe[2], xe[3]);
                *(float4*)(hp + 4) = make_float4(xe[4], xe[5], xe[6], xe[7]);
            }
        } else {
            __syncthreads();   // all encode reads of sBuf done
            #pragma unroll
            for (int j = 0; j < 8; j++) sBuf[(w * 8 + j) * 64 + lane] = xe[j];
            #pragma unroll
            for (int half = 0; half < 2; half++) {
                __syncthreads();   // xe writes done / previous half's sW1 reads done
                {
                    const float4* src = (const float4*)(W1 + (t * 64 + half * 32) * cHID);
                    float4* dst = (float4*)sW1;
                    dst[tid] = src[tid];
                    dst[tid + 512] = src[tid + 512];
                }
                __syncthreads();
                #pragma unroll 4
                for (int g = 0; g < 32; g++) {
                    float xv = sBuf[(half * 32 + g) * 64 + lane];
                    const float* wp = &sW1[g * cHID + w * 16];
                    #pragma unroll
                    for (int j = 0; j < 16; j++) acc[j] = fmaf(xv, wp[j], acc[j]);
                }
            }
        }
    }
    if (has) {
        float* ap = accbuf + (nodeBase + lane) * cHID + w * 16;
        #pragma unroll
        for (int j = 0; j < 16; j += 4)
            *(float4*)(ap + j) = make_float4(acc[j], acc[j + 1], acc[j + 2], acc[j + 3]);
    }
}

// ---------- CSR build (by destination / col) ----------
__global__ void k_count(const int* __restrict__ edges, const int* __restrict__ flag,
                        int* __restrict__ cnt_in) {
    int e = blockIdx.x * 256 + threadIdx.x;
    if (e < cE) {
        int m = *flag;
        atomicAdd(&cnt_in[edges[m * (cE + e)]], 1);
    }
}

__global__ void k_dinv(const int* __restrict__ cnt_in, float* __restrict__ dinv) {
    int n = blockIdx.x * 256 + threadIdx.x;
    if (n < cN) dinv[n] = rsqrtf((float)(cnt_in[n] + 1));   // +1 self-loop
}

// single-block exclusive scan of cnt_in[0..N) -> rowptr[0..N]
__global__ void k_scan(const int* __restrict__ cnt_in, int* __restrict__ rowptr) {
    __shared__ int sdata[1024];
    __shared__ int carry;
    if (threadIdx.x == 0) carry = 0;
    __syncthreads();
    for (int base = 0; base < cN; base += 1024) {
        int i = base + threadIdx.x;
        int v = (i < cN) ? cnt_in[i] : 0;
        sdata[threadIdx.x] = v;
        __syncthreads();
        for (int off = 1; off < 1024; off <<= 1) {
            int t = (threadIdx.x >= off) ? sdata[threadIdx.x - off] : 0;
            __syncthreads();
            sdata[threadIdx.x] += t;
            __syncthreads();
        }
        if (i < cN) rowptr[i] = carry + sdata[threadIdx.x] - v;   // exclusive
        __syncthreads();
        if (threadIdx.x == 1023) carry += sdata[1023];
        __syncthreads();
    }
    if (threadIdx.x == 0) rowptr[cN] = carry;   // == E
}

__global__ void k_fill(const int* __restrict__ edges, const int* __restrict__ flag,
                       const int* __restrict__ rowptr, int* __restrict__ cursor,
                       int* __restrict__ csr_src) {
    int e = blockIdx.x * 256 + threadIdx.x;
    if (e < cE) {
        int m = *flag;
        int r = edges[m * e];
        int c = edges[m * (cE + e)];
        int pos = atomicAdd(&cursor[c], 1);
        csr_src[rowptr[c] + pos] = r;
    }
}

// ---------- GCN step ----------
// xfc = h @ W_fc
__global__ void k_fc(const float* __restrict__ h, const float* __restrict__ W_fc,
                     float* __restrict__ xfc) {
    int g = threadIdx.x & 63, sub = threadIdx.x >> 6;
    int pair = blockIdx.x * 4 + sub;
    __shared__ float sh[4][64];
    bool ok = pair < cB * cN;
    float hv = 0.f;
    if (ok) hv = h[pair * 64 + g];
    sh[sub][g] = hv;
    __syncthreads();
    if (!ok) return;
    float a = 0.f;
    for (int f = 0; f < 64; f++) a = fmaf(sh[sub][f], W_fc[f * 64 + g], a);
    xfc[pair * 64 + g] = a;
}

// hnext[b,n,:] = b_gcn + dinv[n]^2 * xfc[b,n,:] + sum_in dinv[n]*dinv[s]*xfc[b,s,:]
__launch_bounds__(256)
__global__ void k_gather(const int* __restrict__ rowptr, const int* __restrict__ csr_src,
                         const float* __restrict__ dinv, const float* __restrict__ xfc,
                         const float* __restrict__ b_gcn, float* __restrict__ hnext) {
    int wid = blockIdx.x * 4 + (threadIdx.x >> 6);   // b*N + n
    if (wid >= cB * cN) return;
    int lane = threadIdx.x & 63;
    int b = wid / cN, n = wid % cN;
    float di = dinv[n];
    const float* xb = xfc + (size_t)b * cN * 64;
    float acc = fmaf(di * di, xb[n * 64 + lane], b_gcn[lane]);
    int i = rowptr[n], end = rowptr[n + 1];
    int s_next = (i < end) ? csr_src[i] : 0;
    while (i < end) {
        int s = s_next;
        ++i;
        s_next = (i < end) ? csr_src[i] : 0;
        acc = fmaf(di * dinv[s], xb[s * 64 + lane], acc);
    }
    hnext[wid * 64 + lane] = acc;
}

// ---------- head: out = relu(acc + h_fin@W1_{T-1} + b1) @ W2 + b2 ----------
__global__ void k_head(const float* __restrict__ accbuf, const float* __restrict__ hfin,
                       const float* __restrict__ W1, const float* __restrict__ b1,
                       const float* __restrict__ W2, const float* __restrict__ b2,
                       float* __restrict__ out) {
    int pair = blockIdx.x;
    int j = threadIdx.x;   // 0..127
    __shared__ float sh[64];
    __shared__ float red[128];
    if (j < 64) sh[j] = hfin[pair * 64 + j];
    __syncthreads();
    float a = accbuf[pair * cHID + j] + b1[j];
    const float* wp = W1 + (cT - 1) * 64 * cHID + j;
    for (int f = 0; f < 64; f++) a = fmaf(sh[f], wp[f * cHID], a);
    a = fmaxf(a, 0.f) * W2[j];
    red[j] = a;
    __syncthreads();
    for (int s = 64; s > 0; s >>= 1) {
        if (j < s) red[j] += red[j + s];
        __syncthreads();
    }
    if (j == 0) out[pair] = red[0] + b2[0];
}

extern "C" void kernel_launch(void* const* d_in, const int* in_sizes, int n_in,
                              void* d_out, int out_size, void* d_ws, size_t ws_size,
                              hipStream_t stream) {
    const float* history = (const float*)d_in[0];
    const float* horizon = (const float*)d_in[1];
    const int*   edges   = (const int*)d_in[2];
    const float* W_enc   = (const float*)d_in[3];
    const float* W_hor   = (const float*)d_in[4];
    const float* b_enc   = (const float*)d_in[5];
    const float* W_fc    = (const float*)d_in[6];
    const float* b_gcn   = (const float*)d_in[7];
    const float* W1      = (const float*)d_in[8];
    const float* b1      = (const float*)d_in[9];
    const float* W2      = (const float*)d_in[10];
    const float* b2      = (const float*)d_in[11];
    float* out = (float*)d_out;

    float* ws = (float*)d_ws;
    float* hc     = ws;                               // B*N*64
    float* accbuf = hc + (size_t)cB * cN * 64;        // B*N*128
    float* h0     = accbuf + (size_t)cB * cN * cHID;  // B*N*64
    float* h1     = h0 + (size_t)cB * cN * 64;        // B*N*64
    float* xfc    = h1 + (size_t)cB * cN * 64;        // B*N*64
    float* dinv   = xfc + (size_t)cB * cN * 64;       // N
    int*   cnt_in = (int*)(dinv + cN);                // N
    int*   cursor = cnt_in + cN;                      // N
    int*   rowptr = cursor + cN;                      // N+1
    int*   csr_src= rowptr + cN + 1;                  // E
    int*   cnt    = csr_src + cE;
    int*   flag   = cnt + 1;

    k_zero<<<1, 1, 0, stream>>>(cnt);
    k_detect<<<(cE + 255) / 256, 256, 0, stream>>>(edges, cnt);
    k_flag<<<1, 1, 0, stream>>>(cnt, flag);

    k_hc<<<(cB * cN + 3) / 4, 256, 0, stream>>>(horizon, W_hor, b_enc, hc);
    k_encode_mlp<<<dim3((cN + 63) / 64, cB), 512, 0, stream>>>(history, W_enc, hc, W1, accbuf, h0);

    hipMemsetAsync(cnt_in, 0, cN * sizeof(int), stream);
    hipMemsetAsync(cursor, 0, cN * sizeof(int), stream);
    k_count<<<(cE + 255) / 256, 256, 0, stream>>>(edges, flag, cnt_in);
    k_dinv<<<(cN + 255) / 256, 256, 0, stream>>>(cnt_in, dinv);
    k_scan<<<1, 1024, 0, stream>>>(cnt_in, rowptr);
    k_fill<<<(cE + 255) / 256, 256, 0, stream>>>(edges, flag, rowptr, cursor, csr_src);

    float* hin = h0; float* hout = h1;
    for (int s = 0; s < cK; s++) {
        k_fc<<<(cB * cN + 3) / 4, 256, 0, stream>>>(hin, W_fc, xfc);
        k_gather<<<(cB * cN + 3) / 4, 256, 0, stream>>>(rowptr, csr_src, dinv, xfc, b_gcn, hout);
        float* tmp = hin; hin = hout; hout = tmp;
    }

    k_head<<<cB * cN, 128, 0, stream>>>(accbuf, hin, W1, b1, W2, b2, out);
}

// Round 3
// 415.706 us; speedup vs baseline: 5.9321x; 2.3903x over previous
//
#include <hip/hip_runtime.h>

// STGAN fused forward for MI355X. Shapes fixed per reference.
constexpr int cB = 4, cT = 24, cN = 10000, cF = 64, cE = 160000, cHID = 128, cK = 3;

typedef short s16x4 __attribute__((ext_vector_type(4)));
typedef short s16x8 __attribute__((ext_vector_type(8)));
typedef float f32x16 __attribute__((ext_vector_type(16)));

__device__ __forceinline__ unsigned short f2bf(float f) {
    union { float f; unsigned u; } c; c.f = f;
    unsigned u = c.u;
    return (unsigned short)((u + 0x7FFFu + ((u >> 16) & 1u)) >> 16);
}

__device__ __forceinline__ float tanh_fast(float x) {
    float e = __expf(2.0f * x);
    return 1.0f - 2.0f * __builtin_amdgcn_rcpf(e + 1.0f);
}

// ---------- edge dtype detection (int32 vs int64 pushed buffer) ----------
__global__ void k_zero(int* c) { *c = 0; }

__global__ void k_detect(const int* __restrict__ edges, int* __restrict__ cnt) {
    int i = blockIdx.x * 256 + threadIdx.x;
    int z = (i < cE && edges[2 * i + 1] == 0) ? 1 : 0;
    __shared__ int sc;
    if (threadIdx.x == 0) sc = 0;
    __syncthreads();
    if (z) atomicAdd(&sc, 1);
    __syncthreads();
    if (threadIdx.x == 0 && sc) atomicAdd(cnt, sc);
}

__global__ void k_flag(const int* __restrict__ cnt, int* __restrict__ flag) {
    *flag = (*cnt > cE - 100) ? 2 : 1;
}

// ---------- W1 pre-transpose: W1T[hid][gp] = bf16(W1[gp][hid]) ----------
__global__ void k_w1t(const float* __restrict__ W1, unsigned short* __restrict__ W1T) {
    __shared__ float sT[64][65];
    const int gx = blockIdx.x * 64;   // gp tile (24)
    const int hx = blockIdx.y * 64;   // hid tile (2)
    const int tid = threadIdx.x;
    #pragma unroll
    for (int r = 0; r < 4; r++) {
        int flat = tid + r * 256;             // float4 idx 0..1023
        int gp = flat >> 4, h4 = (flat & 15) * 4;
        float4 v = *(const float4*)&W1[(size_t)(gx + gp) * cHID + hx + h4];
        sT[h4 + 0][gp] = v.x; sT[h4 + 1][gp] = v.y;
        sT[h4 + 2][gp] = v.z; sT[h4 + 3][gp] = v.w;
    }
    __syncthreads();
    #pragma unroll
    for (int r = 0; r < 2; r++) {
        int flat = tid + r * 256;             // bf16x8 idx 0..511
        int h = flat >> 3, seg = flat & 7;
        s16x8 o;
        #pragma unroll
        for (int i = 0; i < 8; i++) o[i] = (short)f2bf(sT[h][seg * 8 + i]);
        *(s16x8*)&W1T[(size_t)(hx + h) * (cT * 64) + gx + seg * 8] = o;
    }
}

// ---------- hor_ctx = mean(horizon,1) @ W_hor + b_enc ----------
__global__ void k_hc(const float* __restrict__ horizon, const float* __restrict__ W_hor,
                     const float* __restrict__ b_enc, float* __restrict__ hc) {
    int g = threadIdx.x & 63;
    int sub = threadIdx.x >> 6;
    int pair = blockIdx.x * 4 + sub;          // b*N + n
    __shared__ float sm[4][64];
    bool ok = pair < cB * cN;
    float m = 0.f;
    if (ok) {
        int b = pair / cN, n = pair % cN;
        const float* hp = horizon + ((size_t)(b * 6) * cN + n) * 64 + g;
        #pragma unroll
        for (int hh = 0; hh < 6; hh++) m += hp[(size_t)hh * cN * 64];
        m *= (1.0f / 6.0f);
    }
    sm[sub][g] = m;
    __syncthreads();
    if (!ok) return;
    float a = b_enc[g];
    for (int f = 0; f < 64; f++) a = fmaf(sm[sub][f], W_hor[f * 64 + g], a);
    hc[(size_t)pair * 64 + g] = a;
}

// ---------- fused encode + MLP accumulate, bf16 MFMA ----------
// 4 waves / 64-node tile. Encode: wave w -> (mtile=w&1, gtile=w>>1) 32x32 tile,
// D[node][g] = tanh(mfma(hist, W_enc, C=hc)). MLP swapped: acc'[hid][node] +=
// mfma(W1T_frag, XeT_frag), wave w owns hid rows w*32..w*32+31, both node tiles.
__launch_bounds__(256, 3)
__global__ void k_encode_mlp(const float* __restrict__ history,
                             const float* __restrict__ W_enc,
                             const float* __restrict__ hc,
                             const unsigned short* __restrict__ W1T,
                             float* __restrict__ accbuf,
                             float* __restrict__ h0) {
    __shared__ unsigned short sHist[64 * 64];   // [node][f], xor-swizzled, 8KB
    __shared__ unsigned short sXe[64 * 64];     // [node][g], xor-swizzled, 8KB
    __shared__ unsigned short sW1T[128 * 64];   // [hid][g], xor-swizzled, 16KB
    const int tid = threadIdx.x;
    const int lane = tid & 63;
    const int w = tid >> 6;
    const int l31 = lane & 31;
    const int lhi = lane >> 5;
    const int n0 = blockIdx.x * 64;
    const int b = blockIdx.y;
    const int nn = min(64, cN - n0);
    const int mtile = w & 1;
    const int gtile = w >> 1;

    // W_enc B-fragments, register resident (col = gtile*32 + l31)
    s16x8 wenc[4];
    {
        int col = gtile * 32 + l31;
        #pragma unroll
        for (int ks = 0; ks < 4; ks++)
            #pragma unroll
            for (int i = 0; i < 8; i++)
                wenc[ks][i] = (short)f2bf(W_enc[(ks * 16 + lhi * 8 + i) * 64 + col]);
    }
    // hc as loop-invariant C-init
    float hcr[16];
    {
        int col = gtile * 32 + l31;
        #pragma unroll
        for (int reg = 0; reg < 16; reg++) {
            int row = mtile * 32 + (reg & 3) + 8 * (reg >> 2) + 4 * lhi;
            hcr[reg] = (row < nn) ? hc[(size_t)(b * cN + n0 + row) * 64 + col] : 0.f;
        }
    }
    f32x16 accm[2];
    #pragma unroll
    for (int nt = 0; nt < 2; nt++)
        #pragma unroll
        for (int r = 0; r < 16; r++) accm[nt][r] = 0.f;

    for (int t = 0; t < cT; t++) {
        __syncthreads();   // previous readers of sHist/sW1T/sXe done
        {   // stage hist tile fp32->bf16, swizzled
            const float* hsrc = history + ((size_t)(b * cT + t) * cN + n0) * 64;
            #pragma unroll
            for (int r = 0; r < 4; r++) {
                int flat = tid + r * 256;       // float4 idx
                int node = flat >> 4, fq = flat & 15;
                float4 v = make_float4(0.f, 0.f, 0.f, 0.f);
                if (node < nn) v = *(const float4*)(hsrc + node * 64 + fq * 4);
                s16x4 o;
                o[0] = (short)f2bf(v.x); o[1] = (short)f2bf(v.y);
                o[2] = (short)f2bf(v.z); o[3] = (short)f2bf(v.w);
                int idx = (node * 64 + fq * 4) ^ ((node & 7) << 3);
                *(s16x4*)&sHist[idx] = o;
            }
            // stage W1T tile (bf16 direct copy), swizzled
            const unsigned short* wsrc = W1T + t * 64;
            #pragma unroll
            for (int r = 0; r < 4; r++) {
                int flat = tid + r * 256;       // bf16x8 idx 0..1023
                int hid = flat >> 3, seg = flat & 7;
                s16x8 vv = *(const s16x8*)(wsrc + (size_t)hid * (cT * 64) + seg * 8);
                int idx = (hid * 64 + seg * 8) ^ ((hid & 7) << 3);
                *(s16x8*)&sW1T[idx] = vv;
            }
        }
        __syncthreads();
        // encode MFMA: D[node][g], C-init = hc
        f32x16 d;
        #pragma unroll
        for (int reg = 0; reg < 16; reg++) d[reg] = hcr[reg];
        {
            int node = mtile * 32 + l31;
            int base = node * 64 + lhi * 8;
            int sw = (node & 7) << 3;
            #pragma unroll
            for (int ks = 0; ks < 4; ks++) {
                s16x8 a = *(const s16x8*)&sHist[(base + ks * 16) ^ sw];
                d = __builtin_amdgcn_mfma_f32_32x32x16_bf16(a, wenc[ks], d, 0, 0, 0);
            }
        }
        if (t == cT - 1) {
            int col = gtile * 32 + l31;
            #pragma unroll
            for (int reg = 0; reg < 16; reg++) {
                int row = mtile * 32 + (reg & 3) + 8 * (reg >> 2) + 4 * lhi;
                if (row < nn)
                    h0[(size_t)(b * cN + n0 + row) * 64 + col] = tanh_fast(d[reg]);
            }
        } else {
            int col = gtile * 32 + l31;
            #pragma unroll
            for (int reg = 0; reg < 16; reg++) {
                int row = mtile * 32 + (reg & 3) + 8 * (reg >> 2) + 4 * lhi;
                int idx = (row * 64 + col) ^ ((row & 7) << 3);
                sXe[idx] = f2bf(tanh_fast(d[reg]));
            }
            __syncthreads();   // sXe complete
            int hidrow = w * 32 + l31;
            int abase = hidrow * 64 + lhi * 8;
            int swA = (hidrow & 7) << 3;
            #pragma unroll
            for (int nt = 0; nt < 2; nt++) {
                int noderow = nt * 32 + l31;
                int bbase = noderow * 64 + lhi * 8;
                int swB = (noderow & 7) << 3;
                #pragma unroll
                for (int ks = 0; ks < 4; ks++) {
                    s16x8 aw = *(const s16x8*)&sW1T[(abase + ks * 16) ^ swA];
                    s16x8 bx = *(const s16x8*)&sXe[(bbase + ks * 16) ^ swB];
                    accm[nt] = __builtin_amdgcn_mfma_f32_32x32x16_bf16(aw, bx, accm[nt], 0, 0, 0);
                }
            }
        }
    }
    // store acc': lane holds node = nt*32+l31, hid quads
    #pragma unroll
    for (int nt = 0; nt < 2; nt++) {
        int node = nt * 32 + l31;
        if (node < nn) {
            float* ap = accbuf + (size_t)(b * cN + n0 + node) * cHID;
            #pragma unroll
            for (int q = 0; q < 4; q++) {
                int hid0 = w * 32 + q * 8 + lhi * 4;
                float4 v = make_float4(accm[nt][q * 4 + 0], accm[nt][q * 4 + 1],
                                       accm[nt][q * 4 + 2], accm[nt][q * 4 + 3]);
                *(float4*)(ap + hid0) = v;
            }
        }
    }
}

// ---------- CSR build (by destination / col) ----------
__global__ void k_count(const int* __restrict__ edges, const int* __restrict__ flag,
                        int* __restrict__ cnt_in) {
    int e = blockIdx.x * 256 + threadIdx.x;
    if (e < cE) {
        int m = *flag;
        atomicAdd(&cnt_in[edges[m * (cE + e)]], 1);
    }
}

__global__ void k_dinv(const int* __restrict__ cnt_in, float* __restrict__ dinv) {
    int n = blockIdx.x * 256 + threadIdx.x;
    if (n < cN) dinv[n] = rsqrtf((float)(cnt_in[n] + 1));   // +1 self-loop
}

__global__ void k_scan(const int* __restrict__ cnt_in, int* __restrict__ rowptr) {
    __shared__ int sdata[1024];
    __shared__ int carry;
    if (threadIdx.x == 0) carry = 0;
    __syncthreads();
    for (int base = 0; base < cN; base += 1024) {
        int i = base + threadIdx.x;
        int v = (i < cN) ? cnt_in[i] : 0;
        sdata[threadIdx.x] = v;
        __syncthreads();
        for (int off = 1; off < 1024; off <<= 1) {
            int t = (threadIdx.x >= off) ? sdata[threadIdx.x - off] : 0;
            __syncthreads();
            sdata[threadIdx.x] += t;
            __syncthreads();
        }
        if (i < cN) rowptr[i] = carry + sdata[threadIdx.x] - v;   // exclusive
        __syncthreads();
        if (threadIdx.x == 1023) carry += sdata[1023];
        __syncthreads();
    }
    if (threadIdx.x == 0) rowptr[cN] = carry;
}

__global__ void k_fill(const int* __restrict__ edges, const int* __restrict__ flag,
                       const int* __restrict__ rowptr, int* __restrict__ cursor,
                       int* __restrict__ csr_src) {
    int e = blockIdx.x * 256 + threadIdx.x;
    if (e < cE) {
        int m = *flag;
        int r = edges[m * e];
        int c = edges[m * (cE + e)];
        int pos = atomicAdd(&cursor[c], 1);
        csr_src[rowptr[c] + pos] = r;
    }
}

// ---------- GCN step ----------
// xfc[n][b][g] = dinv[n] * (h[b,n,:] @ W_fc)[g]
__global__ void k_fc(const float* __restrict__ h, const float* __restrict__ W_fc,
                     const float* __restrict__ dinv, float* __restrict__ xfc) {
    int n = blockIdx.x;
    int g = threadIdx.x & 63, bb = threadIdx.x >> 6;
    __shared__ float sh[4][64];
    sh[bb][g] = h[(size_t)(bb * cN + n) * 64 + g];
    __syncthreads();
    float a = 0.f;
    #pragma unroll 8
    for (int f = 0; f < 64; f++) a = fmaf(sh[bb][f], W_fc[f * 64 + g], a);
    xfc[(size_t)n * 256 + bb * 64 + g] = dinv[n] * a;
}

// hnext[b,n,:] = b_gcn + dinv[n]*(xfc[n] + sum_in xfc[s]) ; one wave per node, 4 batches
__launch_bounds__(256)
__global__ void k_gather(const int* __restrict__ rowptr, const int* __restrict__ csr_src,
                         const float* __restrict__ dinv, const float* __restrict__ xfc,
                         const float* __restrict__ b_gcn, float* __restrict__ hnext) {
    int n = blockIdx.x * 4 + (threadIdx.x >> 6);
    if (n >= cN) return;
    int g = threadIdx.x & 63;
    const float* xn = xfc + (size_t)n * 256;
    float a0 = xn[g], a1 = xn[64 + g], a2 = xn[128 + g], a3 = xn[192 + g];
    int i = rowptr[n], end = rowptr[n + 1];
    int s_next = (i < end) ? csr_src[i] : 0;
    while (i < end) {
        const float* xs = xfc + (size_t)s_next * 256;
        ++i;
        s_next = (i < end) ? csr_src[i] : 0;
        a0 += xs[g]; a1 += xs[64 + g]; a2 += xs[128 + g]; a3 += xs[192 + g];
    }
    float di = dinv[n], bg = b_gcn[g];
    hnext[(size_t)(0 * cN + n) * 64 + g] = fmaf(di, a0, bg);
    hnext[(size_t)(1 * cN + n) * 64 + g] = fmaf(di, a1, bg);
    hnext[(size_t)(2 * cN + n) * 64 + g] = fmaf(di, a2, bg);
    hnext[(size_t)(3 * cN + n) * 64 + g] = fmaf(di, a3, bg);
}

// ---------- head: out = relu(acc + h_fin@W1_{T-1} + b1) @ W2 + b2 ----------
__global__ void k_head(const float* __restrict__ accbuf, const float* __restrict__ hfin,
                       const float* __restrict__ W1, const float* __restrict__ b1,
                       const float* __restrict__ W2, const float* __restrict__ b2,
                       float* __restrict__ out) {
    int pair = blockIdx.x;
    int j = threadIdx.x;   // 0..127
    __shared__ float sh[64];
    __shared__ float red[128];
    if (j < 64) sh[j] = hfin[(size_t)pair * 64 + j];
    __syncthreads();
    float a = accbuf[(size_t)pair * cHID + j] + b1[j];
    const float* wp = W1 + (size_t)(cT - 1) * 64 * cHID + j;
    for (int f = 0; f < 64; f++) a = fmaf(sh[f], wp[f * cHID], a);
    a = fmaxf(a, 0.f) * W2[j];
    red[j] = a;
    __syncthreads();
    for (int s = 64; s > 0; s >>= 1) {
        if (j < s) red[j] += red[j + s];
        __syncthreads();
    }
    if (j == 0) out[pair] = red[0] + b2[0];
}

extern "C" void kernel_launch(void* const* d_in, const int* in_sizes, int n_in,
                              void* d_out, int out_size, void* d_ws, size_t ws_size,
                              hipStream_t stream) {
    const float* history = (const float*)d_in[0];
    const float* horizon = (const float*)d_in[1];
    const int*   edges   = (const int*)d_in[2];
    const float* W_enc   = (const float*)d_in[3];
    const float* W_hor   = (const float*)d_in[4];
    const float* b_enc   = (const float*)d_in[5];
    const float* W_fc    = (const float*)d_in[6];
    const float* b_gcn   = (const float*)d_in[7];
    const float* W1      = (const float*)d_in[8];
    const float* b1      = (const float*)d_in[9];
    const float* W2      = (const float*)d_in[10];
    const float* b2      = (const float*)d_in[11];
    float* out = (float*)d_out;

    float* ws = (float*)d_ws;
    float* hc     = ws;                                   // B*N*64
    float* accbuf = hc + (size_t)cB * cN * 64;            // B*N*128
    float* h0     = accbuf + (size_t)cB * cN * cHID;      // B*N*64
    float* h1     = h0 + (size_t)cB * cN * 64;            // B*N*64
    float* xfc    = h1 + (size_t)cB * cN * 64;            // N*B*64 (n-major)
    float* dinv   = xfc + (size_t)cB * cN * 64;           // N
    unsigned short* w1t = (unsigned short*)(dinv + cN);   // 128*1536 bf16
    int*   cnt_in = (int*)(w1t + (size_t)cHID * cT * 64); // N
    int*   cursor = cnt_in + cN;                          // N
    int*   rowptr = cursor + cN;                          // N+1
    int*   csr_src= rowptr + cN + 1;                      // E
    int*   cnt    = csr_src + cE;
    int*   flag   = cnt + 1;

    k_zero<<<1, 1, 0, stream>>>(cnt);
    k_detect<<<(cE + 255) / 256, 256, 0, stream>>>(edges, cnt);
    k_flag<<<1, 1, 0, stream>>>(cnt, flag);

    k_w1t<<<dim3(cT * 64 / 64, cHID / 64), 256, 0, stream>>>(W1, w1t);
    k_hc<<<(cB * cN + 3) / 4, 256, 0, stream>>>(horizon, W_hor, b_enc, hc);
    k_encode_mlp<<<dim3((cN + 63) / 64, cB), 256, 0, stream>>>(history, W_enc, hc, w1t, accbuf, h0);

    hipMemsetAsync(cnt_in, 0, cN * sizeof(int), stream);
    hipMemsetAsync(cursor, 0, cN * sizeof(int), stream);
    k_count<<<(cE + 255) / 256, 256, 0, stream>>>(edges, flag, cnt_in);
    k_dinv<<<(cN + 255) / 256, 256, 0, stream>>>(cnt_in, dinv);
    k_scan<<<1, 1024, 0, stream>>>(cnt_in, rowptr);
    k_fill<<<(cE + 255) / 256, 256, 0, stream>>>(edges, flag, rowptr, cursor, csr_src);

    float* hin = h0; float* hout = h1;
    for (int s = 0; s < cK; s++) {
        k_fc<<<cN, 256, 0, stream>>>(hin, W_fc, dinv, xfc);
        k_gather<<<(cN + 3) / 4, 256, 0, stream>>>(rowptr, csr_src, dinv, xfc, b_gcn, hout);
        float* tmp = hin; hin = hout; hout = tmp;
    }

    k_head<<<cB * cN, 128, 0, stream>>>(accbuf, hin, W1, b1, W2, b2, out);
}